// Round 22
// baseline (268.172 us; speedup 1.0000x reference)
//
#include <hip/hip_runtime.h>
#include <stdint.h>

typedef __attribute__((ext_vector_type(8))) short short8;
typedef __attribute__((ext_vector_type(4))) float floatx4;

__device__ __forceinline__ unsigned short f2bf(float x) {
    unsigned int u = __builtin_bit_cast(unsigned int, x);
    unsigned int r = (u + 0x7FFFu + ((u >> 16) & 1u)) >> 16;   // RNE
    return (unsigned short)r;
}
__device__ __forceinline__ float bf2f(unsigned short x) {
    unsigned int u = ((unsigned int)x) << 16;
    return __builtin_bit_cast(float, u);
}

// tanh = (e^2x-1)/(e^2x+1), clamp |x|<=10; rcp + 1 Newton. ~1e-7 rel err.
__device__ __forceinline__ float fast_tanh(float x) {
    float xc = fminf(fmaxf(x, -10.0f), 10.0f);
    float e  = __expf(2.0f * xc);
    float d  = e + 1.0f;
    float r  = __builtin_amdgcn_rcpf(d);
    r = r * (2.0f - d * r);
    return (e - 1.0f) * r;
}

#define VMC(n) asm volatile("s_waitcnt vmcnt(" #n ")" ::: "memory")
#define BAR()  asm volatile("s_barrier" ::: "memory")

// ---- W f32 -> bf16 ----
__global__ void wconv(const float4* __restrict__ W4, ushort4* __restrict__ Wb4) {
    int i = blockIdx.x * 256 + threadIdx.x;
    float4 v = W4[i];
    ushort4 o;
    o.x = f2bf(v.x); o.y = f2bf(v.y); o.z = f2bf(v.z); o.w = f2bf(v.w);
    Wb4[i] = o;
}

// ---- vocab table: embT[v][c] = bf16(tanh(emb[v][c])), 32000x512 ----
__global__ void tconv(const float4* __restrict__ emb4, ushort4* __restrict__ embT4) {
    int i = blockIdx.x * 256 + threadIdx.x;   // 4,096,000 threads exactly
    float4 v = emb4[i];
    ushort4 o;
    o.x = f2bf(fast_tanh(v.x)); o.y = f2bf(fast_tanh(v.y));
    o.z = f2bf(fast_tanh(v.z)); o.w = f2bf(fast_tanh(v.w));
    embT4[i] = o;
}

// ---- level 1 via tables: h1[m] = tanh(P[idL] + Q[idR] + b), 65536x512 bf16 ----
__global__ void lvl1_add(const int* __restrict__ ids, const ushort* __restrict__ PQ,
                         const float* __restrict__ bias, ushort* __restrict__ h1)
{
    int idx = blockIdx.x * 256 + threadIdx.x;   // 4,194,304 threads
    int m = idx >> 6;
    int c = (idx & 63) << 3;
    const int il = ids[2 * m], ir = ids[2 * m + 1];
    const short8 p = *reinterpret_cast<const short8*>(PQ + (size_t)il * 512 + c);
    const short8 q = *reinterpret_cast<const short8*>(PQ + 16384000 + (size_t)ir * 512 + c);
    const float4 b0 = *reinterpret_cast<const float4*>(bias + c);
    const float4 b1 = *reinterpret_cast<const float4*>(bias + c + 4);
    short8 o;
    o[0] = (short)f2bf(fast_tanh(bf2f((unsigned short)p[0]) + bf2f((unsigned short)q[0]) + b0.x));
    o[1] = (short)f2bf(fast_tanh(bf2f((unsigned short)p[1]) + bf2f((unsigned short)q[1]) + b0.y));
    o[2] = (short)f2bf(fast_tanh(bf2f((unsigned short)p[2]) + bf2f((unsigned short)q[2]) + b0.z));
    o[3] = (short)f2bf(fast_tanh(bf2f((unsigned short)p[3]) + bf2f((unsigned short)q[3]) + b0.w));
    o[4] = (short)f2bf(fast_tanh(bf2f((unsigned short)p[4]) + bf2f((unsigned short)q[4]) + b1.x));
    o[5] = (short)f2bf(fast_tanh(bf2f((unsigned short)p[5]) + bf2f((unsigned short)q[5]) + b1.y));
    o[6] = (short)f2bf(fast_tanh(bf2f((unsigned short)p[6]) + bf2f((unsigned short)q[6]) + b1.z));
    o[7] = (short)f2bf(fast_tanh(bf2f((unsigned short)p[7]) + bf2f((unsigned short)q[7]) + b1.w));
    *reinterpret_cast<short8*>(h1 + (size_t)idx * 8) = o;
}

// ======== 256x256-tile GEMM, BK=64, 512 threads (8 waves 2x4) ========
// Round-17 validated. Used ONLY for level 2 (grid 256 = full machine).
#define STG264(buf, k0)                                                         \
    do {                                                                        \
        _Pragma("unroll")                                                       \
        for (int p = 0; p < 4; ++p) {                                           \
            __builtin_amdgcn_global_load_lds(                                   \
                (const __attribute__((address_space(1))) void*)(Ap + (size_t)p * 64 * 1024 + (k0)), \
                (__attribute__((address_space(3))) void*)&sA[buf][p * 4096 + tid * 8], 16, 0, 0); \
            __builtin_amdgcn_global_load_lds(                                   \
                (const __attribute__((address_space(1))) void*)(Bp + (size_t)p * 64 * 1024 + (k0)), \
                (__attribute__((address_space(3))) void*)&sB[buf][p * 4096 + tid * 8], 16, 0, 0); \
        }                                                                       \
    } while (0)

#define CMP264(buf)                                                             \
    do {                                                                        \
        _Pragma("unroll")                                                       \
        for (int ks = 0; ks < 2; ++ks) {                                        \
            const int kq_ = ks * 4 + lh;                                        \
            const int sw_ = ((kq_ ^ (l15 & 7)) << 3);                           \
            short8 a_[8], b_[4];                                                \
            _Pragma("unroll")                                                   \
            for (int ni = 0; ni < 4; ++ni)                                      \
                b_[ni] = *reinterpret_cast<const short8*>(&sB[buf][(rB + ni * 16) * 64 + sw_]); \
            _Pragma("unroll")                                                   \
            for (int mi = 0; mi < 8; ++mi)                                      \
                a_[mi] = *reinterpret_cast<const short8*>(&sA[buf][(rA + mi * 16) * 64 + sw_]); \
            __builtin_amdgcn_s_setprio(1);                                      \
            _Pragma("unroll")                                                   \
            for (int mi = 0; mi < 8; ++mi)                                      \
                _Pragma("unroll")                                               \
                for (int ni = 0; ni < 4; ++ni)                                  \
                    acc[mi][ni] = __builtin_amdgcn_mfma_f32_16x16x32_bf16(      \
                        a_[mi], b_[ni], acc[mi][ni], 0, 0, 0);                  \
            __builtin_amdgcn_s_setprio(0);                                      \
        }                                                                       \
    } while (0)

__global__ __launch_bounds__(512)
void gemm256(const ushort* __restrict__ A, const ushort* __restrict__ Bt,
             const float* __restrict__ bias, ushort* __restrict__ outb)
{
    constexpr int NT = 16;
    __shared__ alignas(16) ushort sA[2][16384];   // [buf][256 rows x 64 elems]
    __shared__ alignas(16) ushort sB[2][16384];   // total 128 KiB

    const int tid  = threadIdx.x;
    const int lane = tid & 63;
    const int w    = tid >> 6;
    const int wr   = w >> 2, wc = w & 3;
    const int l15  = lane & 15;
    const int lh   = lane >> 4;

    const int nb  = gridDim.x;           // 256
    const int per = nb >> 3;
    const int lin = (blockIdx.x & 7) * per + (blockIdx.x >> 3);
    const int mt = lin >> 1, ntile = lin & 1;   // A-panel pair lands on one XCD
    const int m0 = mt * 256, n0 = ntile * 256;

    const int r0 = tid >> 3;
    const int s0 = tid & 7;
    const int swz = ((s0 ^ (r0 & 7)) << 3);
    const ushort* Ap = A  + (size_t)(m0 + r0) * 1024 + swz;
    const ushort* Bp = Bt + (size_t)(n0 + r0) * 1024 + swz;

    const int rA = wr * 128 + l15;
    const int rB = wc * 64  + l15;

    floatx4 acc[8][4] = {};

    STG264(0, 0);
    for (int t = 0; t + 2 < NT; t += 2) {
        BAR(); STG264(1, (t + 1) * 64); VMC(8); CMP264(0);
        BAR(); STG264(0, (t + 2) * 64); VMC(8); CMP264(1);
    }
    BAR(); STG264(1, (NT - 1) * 64); VMC(8); CMP264(0);
    BAR(); VMC(0); CMP264(1);

    const int mrow = lh * 4;
    #pragma unroll
    for (int mi = 0; mi < 8; ++mi) {
        #pragma unroll
        for (int ni = 0; ni < 4; ++ni) {
            const int n = n0 + wc * 64 + ni * 16 + l15;
            #pragma unroll
            for (int j = 0; j < 4; ++j) {
                const int m = m0 + wr * 128 + mi * 16 + mrow + j;
                float v = fast_tanh(acc[mi][ni][j] + bias[n]);
                outb[(size_t)m * 512 + n] = f2bf(v);
            }
        }
    }
}

// ======== 128x128-tile, BK=32, 3-buffer GEMM core macros (validated) ========
#define STAGE_(buf, k0)                                                         \
    do {                                                                        \
        __builtin_amdgcn_global_load_lds(                                       \
            (const __attribute__((address_space(1))) void*)(Ap + (k0)),         \
            (__attribute__((address_space(3))) void*)&sA[buf][tid * 8], 16, 0, 0); \
        __builtin_amdgcn_global_load_lds(                                       \
            (const __attribute__((address_space(1))) void*)(Ap + 64 * 1024 + (k0)), \
            (__attribute__((address_space(3))) void*)&sA[buf][2048 + tid * 8], 16, 0, 0); \
        __builtin_amdgcn_global_load_lds(                                       \
            (const __attribute__((address_space(1))) void*)(Bp + (k0)),         \
            (__attribute__((address_space(3))) void*)&sB[buf][tid * 8], 16, 0, 0); \
        __builtin_amdgcn_global_load_lds(                                       \
            (const __attribute__((address_space(1))) void*)(Bp + 64 * 1024 + (k0)), \
            (__attribute__((address_space(3))) void*)&sB[buf][2048 + tid * 8], 16, 0, 0); \
    } while (0)

// pq variant: A stride 512 (embT rows)
#define STAGE_PQ(buf, k0)                                                       \
    do {                                                                        \
        __builtin_amdgcn_global_load_lds(                                       \
            (const __attribute__((address_space(1))) void*)(Ap + (k0)),         \
            (__attribute__((address_space(3))) void*)&sA[buf][tid * 8], 16, 0, 0); \
        __builtin_amdgcn_global_load_lds(                                       \
            (const __attribute__((address_space(1))) void*)(Ap + 64 * 512 + (k0)), \
            (__attribute__((address_space(3))) void*)&sA[buf][2048 + tid * 8], 16, 0, 0); \
        __builtin_amdgcn_global_load_lds(                                       \
            (const __attribute__((address_space(1))) void*)(Bp + (k0)),         \
            (__attribute__((address_space(3))) void*)&sB[buf][tid * 8], 16, 0, 0); \
        __builtin_amdgcn_global_load_lds(                                       \
            (const __attribute__((address_space(1))) void*)(Bp + 64 * 1024 + (k0)), \
            (__attribute__((address_space(3))) void*)&sB[buf][2048 + tid * 8], 16, 0, 0); \
    } while (0)

#define COMPUTE_(cur)                                                           \
    do {                                                                        \
        short8 a_[4], b_[4];                                                    \
        _Pragma("unroll")                                                       \
        for (int mi = 0; mi < 4; ++mi)                                          \
            a_[mi] = *reinterpret_cast<const short8*>(&sA[cur][(rA + mi * 16) * 32 + kksw]); \
        _Pragma("unroll")                                                       \
        for (int ni = 0; ni < 4; ++ni)                                          \
            b_[ni] = *reinterpret_cast<const short8*>(&sB[cur][(rB + ni * 16) * 32 + kksw]); \
        __builtin_amdgcn_s_setprio(1);                                          \
        _Pragma("unroll")                                                       \
        for (int mi = 0; mi < 4; ++mi)                                          \
            _Pragma("unroll")                                                   \
            for (int ni = 0; ni < 4; ++ni)                                      \
                acc[mi][ni] = __builtin_amdgcn_mfma_f32_16x16x32_bf16(          \
                    a_[mi], b_[ni], acc[mi][ni], 0, 0, 0);                      \
        __builtin_amdgcn_s_setprio(0);                                          \
    } while (0)

// ---- P/Q tables on 128^2/3-buffer core (round-13 validated K=512 loop),
// NEW: 8-way XCD colocation — each embT 128-row panel g has 8 sharers
// (2 tables x 4 ntiles); map them to identical bid%8 (one XCD). Bijective:
// bid<1984: g = 8*(bid>>6)+(bid&7), s=(bid>>3)&7; tail 16 bids: g=248,249.
__global__ __launch_bounds__(256)
void pq128(const ushort* __restrict__ embT, const ushort* __restrict__ Bt,
           ushort* __restrict__ PQ)
{
    __shared__ alignas(16) ushort sA[3][4096];
    __shared__ alignas(16) ushort sB[3][4096];

    const int tid  = threadIdx.x;
    const int lane = tid & 63;
    const int w    = tid >> 6;
    const int wr   = w >> 1, wc = w & 1;

    int g, s;
    {
        const int bid = blockIdx.x;      // 0..1999
        if (bid < 1984) { g = (bid >> 6) * 8 + (bid & 7); s = (bid >> 3) & 7; }
        else            { g = 248 + ((bid - 1984) >> 3);  s = (bid - 1984) & 7; }
    }
    const int table = s >> 2, nt = s & 3;
    const int m0 = g * 128, n0 = nt * 128;
    const int koff = table << 9;
    const size_t obase = (size_t)table * 16384000;

    const int sr    = tid >> 2;
    const int swcol = (((tid & 3) ^ ((tid >> 3) & 3)) << 3);
    const ushort* Ap = embT + (size_t)(m0 + sr) * 512 + swcol;
    const ushort* Bp = Bt + (size_t)(n0 + sr) * 1024 + koff + swcol;

    const int rA   = wr * 64 + (lane & 15);
    const int rB   = wc * 64 + (lane & 15);
    const int kksw = (((lane >> 4) ^ ((lane >> 1) & 3)) << 3);

    floatx4 acc[4][4] = {};

    // 16 K-tiles (round-13 validated sequence)
    STAGE_PQ(0, 0);
    STAGE_PQ(1, 32);
    for (int t = 0; t < 12; t += 3) {
        BAR(); STAGE_PQ(2, (t + 2) * 32); VMC(4); COMPUTE_(0);
        BAR(); STAGE_PQ(0, (t + 3) * 32); VMC(4); COMPUTE_(1);
        BAR(); STAGE_PQ(1, (t + 4) * 32); VMC(4); COMPUTE_(2);
    }
    BAR(); STAGE_PQ(2, 14 * 32); VMC(4); COMPUTE_(0);   // t=12
    BAR(); STAGE_PQ(0, 15 * 32); VMC(4); COMPUTE_(1);   // t=13
    BAR(); VMC(0); COMPUTE_(2);                         // t=14
    BAR(); VMC(0); COMPUTE_(0);                         // t=15

    ushort* outp = PQ + obase;
    const int mrow = (lane >> 4) * 4;
    const int ncol = lane & 15;
    #pragma unroll
    for (int mi = 0; mi < 4; ++mi)
        #pragma unroll
        for (int ni = 0; ni < 4; ++ni) {
            const int n = n0 + wc * 64 + ni * 16 + ncol;
            #pragma unroll
            for (int j = 0; j < 4; ++j) {
                const int m = m0 + wr * 64 + mi * 16 + mrow + j;
                outp[(size_t)m * 512 + n] = f2bf(acc[mi][ni][j]);
            }
        }
}

// ---- levels 3-4: 128^2 3-buffer, K=1024 (round-14 validated) ----
__global__ __launch_bounds__(256)
void level_gemm(const ushort* __restrict__ A, const ushort* __restrict__ Bt,
                const float* __restrict__ bias,
                ushort* __restrict__ outb, int M)
{
    const int nb  = gridDim.x;
    int bid = blockIdx.x;
    const int per = nb >> 3;
    const int lin = (bid & 7) * per + (bid >> 3);  // bijective XCD chunking
    const int mt = lin >> 2, nt = lin & 3;
    const int m0 = mt * 128, n0 = nt * 128;

    __shared__ alignas(16) ushort sA[3][4096];
    __shared__ alignas(16) ushort sB[3][4096];

    const int tid  = threadIdx.x;
    const int lane = tid & 63;
    const int w    = tid >> 6;
    const int wr   = w >> 1, wc = w & 1;

    const int sr    = tid >> 2;
    const int swcol = (((tid & 3) ^ ((tid >> 3) & 3)) << 3);
    const ushort* Ap = A  + (size_t)(m0 + sr) * 1024 + swcol;
    const ushort* Bp = Bt + (size_t)(n0 + sr) * 1024 + swcol;

    const int rA   = wr * 64 + (lane & 15);
    const int rB   = wc * 64 + (lane & 15);
    const int kksw = (((lane >> 4) ^ ((lane >> 1) & 3)) << 3);

    floatx4 acc[4][4] = {};

    STAGE_(0, 0);
    STAGE_(1, 32);
    for (int t = 0; t < 30; t += 3) {
        BAR(); STAGE_(2, (t + 2) * 32); VMC(4); COMPUTE_(0);
        BAR(); STAGE_(0, (t + 3) * 32); VMC(4); COMPUTE_(1);
        BAR(); STAGE_(1, (t + 4) * 32); VMC(4); COMPUTE_(2);
    }
    BAR(); VMC(0); COMPUTE_(0);
    BAR(); VMC(0); COMPUTE_(1);

    const int mrow = (lane >> 4) * 4;
    const int ncol = lane & 15;
    #pragma unroll
    for (int mi = 0; mi < 4; ++mi)
        #pragma unroll
        for (int ni = 0; ni < 4; ++ni) {
            const int n = n0 + wc * 64 + ni * 16 + ncol;
            const float bb = bias[n];
            #pragma unroll
            for (int j = 0; j < 4; ++j) {
                const int m = m0 + wr * 64 + mi * 16 + mrow + j;
                float v = fast_tanh(acc[mi][ni][j] + bb);
                outb[(size_t)m * 512 + n] = f2bf(v);
            }
        }
}

// ---- levels 5..11: 64x64-tile GEMM, grid = (Mout/64) x 8 N-slices ----
__global__ __launch_bounds__(256)
void small_gemm(const ushort* __restrict__ A, const ushort* __restrict__ Bt,
                const float* __restrict__ bias,
                ushort* __restrict__ outb, float* __restrict__ outf, int last)
{
    __shared__ alignas(16) ushort sA[3][4096];
    __shared__ alignas(16) ushort sB[3][4096];

    const int tid  = threadIdx.x;
    const int lane = tid & 63;
    const int w    = tid >> 6;
    const int l15  = lane & 15;
    const int lh   = lane >> 4;

    int mt, nt;
    {
        const int bid = blockIdx.x;
        const int nmt = gridDim.x >> 3;          // M/64
        if (nmt >= 8) {
            const int x = bid & 7, g = bid >> 3;
            nt = g & 7;
            mt = x * (nmt >> 3) + (g >> 3);      // A-panel sharers same XCD
        } else {
            mt = bid >> 3; nt = bid & 7;
        }
    }
    const int m0 = mt * 64, n0 = nt * 64;

    const int r0 = tid >> 3;
    const int s0 = tid & 7;
    const int swz = ((s0 ^ (r0 & 7)) << 3);
    const ushort* Ap = A  + (size_t)(m0 + r0) * 1024 + swz;
    const ushort* Bp = Bt + (size_t)(n0 + r0) * 1024 + swz;

#define STG6(buf, k0)                                                           \
    do {                                                                        \
        __builtin_amdgcn_global_load_lds(                                       \
            (const __attribute__((address_space(1))) void*)(Ap + (k0)),         \
            (__attribute__((address_space(3))) void*)&sA[buf][tid * 8], 16, 0, 0); \
        __builtin_amdgcn_global_load_lds(                                       \
            (const __attribute__((address_space(1))) void*)(Ap + 32 * 1024 + (k0)), \
            (__attribute__((address_space(3))) void*)&sA[buf][2048 + tid * 8], 16, 0, 0); \
        __builtin_amdgcn_global_load_lds(                                       \
            (const __attribute__((address_space(1))) void*)(Bp + (k0)),         \
            (__attribute__((address_space(3))) void*)&sB[buf][tid * 8], 16, 0, 0); \
        __builtin_amdgcn_global_load_lds(                                       \
            (const __attribute__((address_space(1))) void*)(Bp + 32 * 1024 + (k0)), \
            (__attribute__((address_space(3))) void*)&sB[buf][2048 + tid * 8], 16, 0, 0); \
    } while (0)

    const int rb = w * 16 + l15;
    floatx4 acc[4] = {};

#define CMP6(buf)                                                               \
    do {                                                                        \
        _Pragma("unroll")                                                       \
        for (int ks = 0; ks < 2; ++ks) {                                        \
            const int kq = ks * 4 + lh;                                         \
            const short8 b_ = *reinterpret_cast<const short8*>(                 \
                &sB[buf][rb * 64 + ((kq ^ (rb & 7)) << 3)]);                    \
            __builtin_amdgcn_s_setprio(1);                                      \
            _Pragma("unroll")                                                   \
            for (int mi = 0; mi < 4; ++mi) {                                    \
                const int ra = mi * 16 + l15;                                   \
                const short8 a_ = *reinterpret_cast<const short8*>(             \
                    &sA[buf][ra * 64 + ((kq ^ (l15 & 7)) << 3)]);               \
                acc[mi] = __builtin_amdgcn_mfma_f32_16x16x32_bf16(              \
                    a_, b_, acc[mi], 0, 0, 0);                                  \
            }                                                                   \
            __builtin_amdgcn_s_setprio(0);                                      \
        }                                                                       \
    } while (0)

    STG6(0, 0);
    STG6(1, 64);
    for (int t3 = 0; t3 < 12; t3 += 3) {
        BAR(); STG6(2, (t3 + 2) * 64); VMC(4); CMP6(0);
        BAR(); STG6(0, (t3 + 3) * 64); VMC(4); CMP6(1);
        BAR(); STG6(1, (t3 + 4) * 64); VMC(4); CMP6(2);
    }
    BAR(); STG6(2, 14 * 64); VMC(8); CMP6(0);
    BAR(); STG6(0, 15 * 64); VMC(8); CMP6(1);
    BAR(); VMC(4); CMP6(2);
    BAR(); VMC(0); CMP6(0);
#undef CMP6
#undef STG6

    const int n  = n0 + w * 16 + l15;
    const float bb = bias[n];
    #pragma unroll
    for (int mi = 0; mi < 4; ++mi) {
        #pragma unroll
        for (int j = 0; j < 4; ++j) {
            const int m = m0 + mi * 16 + lh * 4 + j;
            float v = fast_tanh(acc[mi][j] + bb);
            if (last) outf[(size_t)m * 512 + n] = v;
            else      outb[(size_t)m * 512 + n] = f2bf(v);
        }
    }
}

extern "C" void kernel_launch(void* const* d_in, const int* in_sizes, int n_in,
                              void* d_out, int out_size, void* d_ws, size_t ws_size,
                              hipStream_t stream) {
    const int*   ids  = (const int*)d_in[0];
    const float* emb  = (const float*)d_in[1];
    const float* W    = (const float*)d_in[2];
    const float* bias = (const float*)d_in[3];
    float* out = (float*)d_out;

    // ws (ushorts): Wb 524288 | embT 16384000 | PQ 32768000 | hB 33554432 | hA 16777216
    unsigned short* Wb   = (unsigned short*)d_ws;
    unsigned short* embT = Wb + 524288;
    unsigned short* PQ   = embT + 16384000;
    unsigned short* hB   = PQ + 32768000;
    unsigned short* hA   = hB + 33554432;

    wconv<<<512, 256, 0, stream>>>((const float4*)W, (ushort4*)Wb);
    tconv<<<16000, 256, 0, stream>>>((const float4*)emb, (ushort4*)embT);

    // P,Q tables: 2 x [32000 x 512], 128^2 tiles, 3 blocks/CU, 8-way colocation
    pq128<<<2000, 256, 0, stream>>>(embT, Wb, PQ);
    lvl1_add<<<16384, 256, 0, stream>>>(ids, PQ, bias, hB);   // level 1 -> hB

    // level 2 (M=32768): 256-tile grid 256 = full machine (NT=16)
    gemm256<<<256, 512, 0, stream>>>(hB, Wb, bias, hA);

    // levels 3-4 (M=16384, 8192): 128-tile, 3 blocks/CU occupancy
    level_gemm<<<512, 256, 0, stream>>>(hA, Wb, bias, hB, 16384);   // lev3 -> hB
    level_gemm<<<256, 256, 0, stream>>>(hB, Wb, bias, hA, 8192);    // lev4 -> hA

    // levels 5..11: Mout = 4096..64; grid = (Mout/64)*8; ping-pong from hA
    int M = 4096;
    for (int l = 5; l <= 11; ++l) {
        const unsigned short* in = (l & 1) ? hA : hB;
        unsigned short*       ob = (l & 1) ? hB : hA;
        small_gemm<<<(M / 64) * 8, 256, 0, stream>>>(in, Wb, bias, ob, out,
                                                     l == 11 ? 1 : 0);
        M >>= 1;
    }
}

// Round 23
// 255.893 us; speedup vs baseline: 1.0480x; 1.0480x over previous
//
#include <hip/hip_runtime.h>
#include <stdint.h>

typedef __attribute__((ext_vector_type(8))) short short8;
typedef __attribute__((ext_vector_type(4))) float floatx4;

__device__ __forceinline__ unsigned short f2bf(float x) {
    unsigned int u = __builtin_bit_cast(unsigned int, x);
    unsigned int r = (u + 0x7FFFu + ((u >> 16) & 1u)) >> 16;   // RNE
    return (unsigned short)r;
}
__device__ __forceinline__ float bf2f(unsigned short x) {
    unsigned int u = ((unsigned int)x) << 16;
    return __builtin_bit_cast(float, u);
}

// tanh = (e^2x-1)/(e^2x+1), clamp |x|<=10; rcp + 1 Newton. ~1e-7 rel err.
__device__ __forceinline__ float fast_tanh(float x) {
    float xc = fminf(fmaxf(x, -10.0f), 10.0f);
    float e  = __expf(2.0f * xc);
    float d  = e + 1.0f;
    float r  = __builtin_amdgcn_rcpf(d);
    r = r * (2.0f - d * r);
    return (e - 1.0f) * r;
}

#define VMC(n) asm volatile("s_waitcnt vmcnt(" #n ")" ::: "memory")
#define BAR()  asm volatile("s_barrier" ::: "memory")

// ---- W f32 -> bf16 ----
__global__ void wconv(const float4* __restrict__ W4, ushort4* __restrict__ Wb4) {
    int i = blockIdx.x * 256 + threadIdx.x;
    float4 v = W4[i];
    ushort4 o;
    o.x = f2bf(v.x); o.y = f2bf(v.y); o.z = f2bf(v.z); o.w = f2bf(v.w);
    Wb4[i] = o;
}

// ---- vocab table: embT[v][c] = bf16(tanh(emb[v][c])), 32000x512 ----
__global__ void tconv(const float4* __restrict__ emb4, ushort4* __restrict__ embT4) {
    int i = blockIdx.x * 256 + threadIdx.x;   // 4,096,000 threads exactly
    float4 v = emb4[i];
    ushort4 o;
    o.x = f2bf(fast_tanh(v.x)); o.y = f2bf(fast_tanh(v.y));
    o.z = f2bf(fast_tanh(v.z)); o.w = f2bf(fast_tanh(v.w));
    embT4[i] = o;
}

// ---- level 1 via tables: h1[m] = tanh(P[idL] + Q[idR] + b), 65536x512 bf16 ----
__global__ void lvl1_add(const int* __restrict__ ids, const ushort* __restrict__ PQ,
                         const float* __restrict__ bias, ushort* __restrict__ h1)
{
    int idx = blockIdx.x * 256 + threadIdx.x;   // 4,194,304 threads
    int m = idx >> 6;
    int c = (idx & 63) << 3;
    const int il = ids[2 * m], ir = ids[2 * m + 1];
    const short8 p = *reinterpret_cast<const short8*>(PQ + (size_t)il * 512 + c);
    const short8 q = *reinterpret_cast<const short8*>(PQ + 16384000 + (size_t)ir * 512 + c);
    const float4 b0 = *reinterpret_cast<const float4*>(bias + c);
    const float4 b1 = *reinterpret_cast<const float4*>(bias + c + 4);
    short8 o;
    o[0] = (short)f2bf(fast_tanh(bf2f((unsigned short)p[0]) + bf2f((unsigned short)q[0]) + b0.x));
    o[1] = (short)f2bf(fast_tanh(bf2f((unsigned short)p[1]) + bf2f((unsigned short)q[1]) + b0.y));
    o[2] = (short)f2bf(fast_tanh(bf2f((unsigned short)p[2]) + bf2f((unsigned short)q[2]) + b0.z));
    o[3] = (short)f2bf(fast_tanh(bf2f((unsigned short)p[3]) + bf2f((unsigned short)q[3]) + b0.w));
    o[4] = (short)f2bf(fast_tanh(bf2f((unsigned short)p[4]) + bf2f((unsigned short)q[4]) + b1.x));
    o[5] = (short)f2bf(fast_tanh(bf2f((unsigned short)p[5]) + bf2f((unsigned short)q[5]) + b1.y));
    o[6] = (short)f2bf(fast_tanh(bf2f((unsigned short)p[6]) + bf2f((unsigned short)q[6]) + b1.z));
    o[7] = (short)f2bf(fast_tanh(bf2f((unsigned short)p[7]) + bf2f((unsigned short)q[7]) + b1.w));
    *reinterpret_cast<short8*>(h1 + (size_t)idx * 8) = o;
}

// ======== 256x256-tile GEMM, BK=64, 512 threads (8 waves 2x4) ========
// Round-17/19 validated best config. MODE 1 (pq): 4-way colocating bijection
// (round-19 win: FETCH 67->26 MB). Used where grid >= 256 blocks.
#define STG264(buf, k0)                                                         \
    do {                                                                        \
        _Pragma("unroll")                                                       \
        for (int p = 0; p < 4; ++p) {                                           \
            __builtin_amdgcn_global_load_lds(                                   \
                (const __attribute__((address_space(1))) void*)(Ap + (size_t)p * 64 * ASTR + (k0)), \
                (__attribute__((address_space(3))) void*)&sA[buf][p * 4096 + tid * 8], 16, 0, 0); \
            __builtin_amdgcn_global_load_lds(                                   \
                (const __attribute__((address_space(1))) void*)(Bp + (size_t)p * 64 * 1024 + (k0)), \
                (__attribute__((address_space(3))) void*)&sB[buf][p * 4096 + tid * 8], 16, 0, 0); \
        }                                                                       \
    } while (0)

#define CMP264(buf)                                                             \
    do {                                                                        \
        _Pragma("unroll")                                                       \
        for (int ks = 0; ks < 2; ++ks) {                                        \
            const int kq_ = ks * 4 + lh;                                        \
            const int sw_ = ((kq_ ^ (l15 & 7)) << 3);                           \
            short8 a_[8], b_[4];                                                \
            _Pragma("unroll")                                                   \
            for (int ni = 0; ni < 4; ++ni)                                      \
                b_[ni] = *reinterpret_cast<const short8*>(&sB[buf][(rB + ni * 16) * 64 + sw_]); \
            _Pragma("unroll")                                                   \
            for (int mi = 0; mi < 8; ++mi)                                      \
                a_[mi] = *reinterpret_cast<const short8*>(&sA[buf][(rA + mi * 16) * 64 + sw_]); \
            __builtin_amdgcn_s_setprio(1);                                      \
            _Pragma("unroll")                                                   \
            for (int mi = 0; mi < 8; ++mi)                                      \
                _Pragma("unroll")                                               \
                for (int ni = 0; ni < 4; ++ni)                                  \
                    acc[mi][ni] = __builtin_amdgcn_mfma_f32_16x16x32_bf16(      \
                        a_[mi], b_[ni], acc[mi][ni], 0, 0, 0);                  \
            __builtin_amdgcn_s_setprio(0);                                      \
        }                                                                       \
    } while (0)

template<int ASTR, int NT, int MODE>
__global__ __launch_bounds__(512)
void gemm256(const ushort* __restrict__ A, const ushort* __restrict__ Bt,
             const float* __restrict__ bias, ushort* __restrict__ outb)
{
    __shared__ alignas(16) ushort sA[2][16384];   // [buf][256 rows x 64 elems]
    __shared__ alignas(16) ushort sB[2][16384];   // total 128 KiB

    const int tid  = threadIdx.x;
    const int lane = tid & 63;
    const int w    = tid >> 6;
    const int wr   = w >> 2, wc = w & 3;
    const int l15  = lane & 15;
    const int lh   = lane >> 4;

    int mt, ntile, koff = 0;
    size_t obase = 0;
    if constexpr (MODE == 0) {
        const int nb  = gridDim.x;       // multiple of 8
        const int per = nb >> 3;
        const int lin = (blockIdx.x & 7) * per + (blockIdx.x >> 3);
        mt = lin >> 1; ntile = lin & 1;  // A-panel pair lands on one XCD
    } else {
        // 4-way colocation: bids {b,b+8,b+16,b+24} share one mt (same XCD).
        const int bid = blockIdx.x;      // 0..499
        int g, sel;
        if (bid < 480) { g = (bid >> 5) * 8 + (bid & 7); sel = (bid >> 3) & 3; }
        else           { g = 120 + ((bid - 480) >> 2);   sel = (bid - 480) & 3; }
        const int table = sel >> 1;
        mt = g; ntile = sel & 1;
        koff  = table << 9;
        obase = (size_t)table * 16384000;
    }
    const int m0 = mt * 256, n0 = ntile * 256;

    const int r0 = tid >> 3;
    const int s0 = tid & 7;
    const int swz = ((s0 ^ (r0 & 7)) << 3);
    const ushort* Ap = A  + (size_t)(m0 + r0) * ASTR + swz;
    const ushort* Bp = Bt + (size_t)(n0 + r0) * 1024 + koff + swz;

    const int rA = wr * 128 + l15;
    const int rB = wc * 64  + l15;

    floatx4 acc[8][4] = {};

    STG264(0, 0);
    for (int t = 0; t + 2 < NT; t += 2) {
        BAR(); STG264(1, (t + 1) * 64); VMC(8); CMP264(0);
        BAR(); STG264(0, (t + 2) * 64); VMC(8); CMP264(1);
    }
    BAR(); STG264(1, (NT - 1) * 64); VMC(8); CMP264(0);
    BAR(); VMC(0); CMP264(1);

    const int mrow = lh * 4;
    #pragma unroll
    for (int mi = 0; mi < 8; ++mi) {
        #pragma unroll
        for (int ni = 0; ni < 4; ++ni) {
            const int n = n0 + wc * 64 + ni * 16 + l15;
            #pragma unroll
            for (int j = 0; j < 4; ++j) {
                const int m = m0 + wr * 128 + mi * 16 + mrow + j;
                if constexpr (MODE == 0) {
                    float v = fast_tanh(acc[mi][ni][j] + bias[n]);
                    outb[(size_t)m * 512 + n] = f2bf(v);
                } else {
                    outb[obase + (size_t)m * 512 + n] = f2bf(acc[mi][ni][j]);
                }
            }
        }
    }
}

// ======== 128x128-tile, BK=32, 3-buffer GEMM (round-14 validated) ========
// For levels 3-4: grids 512/256, 48 KB LDS -> 3 blocks/CU hides latency.
#define STAGE_(buf, k0)                                                         \
    do {                                                                        \
        __builtin_amdgcn_global_load_lds(                                       \
            (const __attribute__((address_space(1))) void*)(Ap + (k0)),         \
            (__attribute__((address_space(3))) void*)&sA[buf][tid * 8], 16, 0, 0); \
        __builtin_amdgcn_global_load_lds(                                       \
            (const __attribute__((address_space(1))) void*)(Ap + 64 * 1024 + (k0)), \
            (__attribute__((address_space(3))) void*)&sA[buf][2048 + tid * 8], 16, 0, 0); \
        __builtin_amdgcn_global_load_lds(                                       \
            (const __attribute__((address_space(1))) void*)(Bp + (k0)),         \
            (__attribute__((address_space(3))) void*)&sB[buf][tid * 8], 16, 0, 0); \
        __builtin_amdgcn_global_load_lds(                                       \
            (const __attribute__((address_space(1))) void*)(Bp + 64 * 1024 + (k0)), \
            (__attribute__((address_space(3))) void*)&sB[buf][2048 + tid * 8], 16, 0, 0); \
    } while (0)

#define COMPUTE_(cur)                                                           \
    do {                                                                        \
        short8 a_[4], b_[4];                                                    \
        _Pragma("unroll")                                                       \
        for (int mi = 0; mi < 4; ++mi)                                          \
            a_[mi] = *reinterpret_cast<const short8*>(&sA[cur][(rA + mi * 16) * 32 + kksw]); \
        _Pragma("unroll")                                                       \
        for (int ni = 0; ni < 4; ++ni)                                          \
            b_[ni] = *reinterpret_cast<const short8*>(&sB[cur][(rB + ni * 16) * 32 + kksw]); \
        __builtin_amdgcn_s_setprio(1);                                          \
        _Pragma("unroll")                                                       \
        for (int mi = 0; mi < 4; ++mi)                                          \
            _Pragma("unroll")                                                   \
            for (int ni = 0; ni < 4; ++ni)                                      \
                acc[mi][ni] = __builtin_amdgcn_mfma_f32_16x16x32_bf16(          \
                    a_[mi], b_[ni], acc[mi][ni], 0, 0, 0);                      \
        __builtin_amdgcn_s_setprio(0);                                          \
    } while (0)

__global__ __launch_bounds__(256)
void level_gemm(const ushort* __restrict__ A, const ushort* __restrict__ Bt,
                const float* __restrict__ bias,
                ushort* __restrict__ outb, int M)
{
    const int nb  = gridDim.x;
    int bid = blockIdx.x;
    const int per = nb >> 3;
    const int lin = (bid & 7) * per + (bid >> 3);  // bijective XCD chunking
    const int mt = lin >> 2, nt = lin & 3;
    const int m0 = mt * 128, n0 = nt * 128;

    __shared__ alignas(16) ushort sA[3][4096];
    __shared__ alignas(16) ushort sB[3][4096];

    const int tid  = threadIdx.x;
    const int lane = tid & 63;
    const int w    = tid >> 6;
    const int wr   = w >> 1, wc = w & 1;

    const int sr    = tid >> 2;
    const int swcol = (((tid & 3) ^ ((tid >> 3) & 3)) << 3);
    const ushort* Ap = A  + (size_t)(m0 + sr) * 1024 + swcol;
    const ushort* Bp = Bt + (size_t)(n0 + sr) * 1024 + swcol;

    const int rA   = wr * 64 + (lane & 15);
    const int rB   = wc * 64 + (lane & 15);
    const int kksw = (((lane >> 4) ^ ((lane >> 1) & 3)) << 3);

    floatx4 acc[4][4] = {};

    STAGE_(0, 0);
    STAGE_(1, 32);
    for (int t = 0; t < 30; t += 3) {
        BAR(); STAGE_(2, (t + 2) * 32); VMC(4); COMPUTE_(0);
        BAR(); STAGE_(0, (t + 3) * 32); VMC(4); COMPUTE_(1);
        BAR(); STAGE_(1, (t + 4) * 32); VMC(4); COMPUTE_(2);
    }
    BAR(); VMC(0); COMPUTE_(0);
    BAR(); VMC(0); COMPUTE_(1);

    const int mrow = (lane >> 4) * 4;
    const int ncol = lane & 15;
    #pragma unroll
    for (int mi = 0; mi < 4; ++mi)
        #pragma unroll
        for (int ni = 0; ni < 4; ++ni) {
            const int n = n0 + wc * 64 + ni * 16 + ncol;
            const float bb = bias[n];
            #pragma unroll
            for (int j = 0; j < 4; ++j) {
                const int m = m0 + wr * 64 + mi * 16 + mrow + j;
                float v = fast_tanh(acc[mi][ni][j] + bb);
                outb[(size_t)m * 512 + n] = f2bf(v);
            }
        }
}

// ---- levels 5..11: 64x64-tile GEMM, grid = (Mout/64) x 8 N-slices ----
__global__ __launch_bounds__(256)
void small_gemm(const ushort* __restrict__ A, const ushort* __restrict__ Bt,
                const float* __restrict__ bias,
                ushort* __restrict__ outb, float* __restrict__ outf, int last)
{
    __shared__ alignas(16) ushort sA[3][4096];
    __shared__ alignas(16) ushort sB[3][4096];

    const int tid  = threadIdx.x;
    const int lane = tid & 63;
    const int w    = tid >> 6;
    const int l15  = lane & 15;
    const int lh   = lane >> 4;
    const int mt   = blockIdx.x >> 3, nt = blockIdx.x & 7;
    const int m0   = mt * 64, n0 = nt * 64;

    const int r0 = tid >> 3;
    const int s0 = tid & 7;
    const int swz = ((s0 ^ (r0 & 7)) << 3);
    const ushort* Ap = A  + (size_t)(m0 + r0) * 1024 + swz;
    const ushort* Bp = Bt + (size_t)(n0 + r0) * 1024 + swz;

#define STG6(buf, k0)                                                           \
    do {                                                                        \
        __builtin_amdgcn_global_load_lds(                                       \
            (const __attribute__((address_space(1))) void*)(Ap + (k0)),         \
            (__attribute__((address_space(3))) void*)&sA[buf][tid * 8], 16, 0, 0); \
        __builtin_amdgcn_global_load_lds(                                       \
            (const __attribute__((address_space(1))) void*)(Ap + 32 * 1024 + (k0)), \
            (__attribute__((address_space(3))) void*)&sA[buf][2048 + tid * 8], 16, 0, 0); \
        __builtin_amdgcn_global_load_lds(                                       \
            (const __attribute__((address_space(1))) void*)(Bp + (k0)),         \
            (__attribute__((address_space(3))) void*)&sB[buf][tid * 8], 16, 0, 0); \
        __builtin_amdgcn_global_load_lds(                                       \
            (const __attribute__((address_space(1))) void*)(Bp + 32 * 1024 + (k0)), \
            (__attribute__((address_space(3))) void*)&sB[buf][2048 + tid * 8], 16, 0, 0); \
    } while (0)

    const int rb = w * 16 + l15;
    floatx4 acc[4] = {};

#define CMP6(buf)                                                               \
    do {                                                                        \
        _Pragma("unroll")                                                       \
        for (int ks = 0; ks < 2; ++ks) {                                        \
            const int kq = ks * 4 + lh;                                         \
            const short8 b_ = *reinterpret_cast<const short8*>(                 \
                &sB[buf][rb * 64 + ((kq ^ (rb & 7)) << 3)]);                    \
            __builtin_amdgcn_s_setprio(1);                                      \
            _Pragma("unroll")                                                   \
            for (int mi = 0; mi < 4; ++mi) {                                    \
                const int ra = mi * 16 + l15;                                   \
                const short8 a_ = *reinterpret_cast<const short8*>(             \
                    &sA[buf][ra * 64 + ((kq ^ (l15 & 7)) << 3)]);               \
                acc[mi] = __builtin_amdgcn_mfma_f32_16x16x32_bf16(              \
                    a_, b_, acc[mi], 0, 0, 0);                                  \
            }                                                                   \
            __builtin_amdgcn_s_setprio(0);                                      \
        }                                                                       \
    } while (0)

    STG6(0, 0);
    STG6(1, 64);
    for (int t3 = 0; t3 < 12; t3 += 3) {
        BAR(); STG6(2, (t3 + 2) * 64); VMC(4); CMP6(0);
        BAR(); STG6(0, (t3 + 3) * 64); VMC(4); CMP6(1);
        BAR(); STG6(1, (t3 + 4) * 64); VMC(4); CMP6(2);
    }
    BAR(); STG6(2, 14 * 64); VMC(8); CMP6(0);
    BAR(); STG6(0, 15 * 64); VMC(8); CMP6(1);
    BAR(); VMC(4); CMP6(2);
    BAR(); VMC(0); CMP6(0);
#undef CMP6
#undef STG6

    const int n  = n0 + w * 16 + l15;
    const float bb = bias[n];
    #pragma unroll
    for (int mi = 0; mi < 4; ++mi) {
        #pragma unroll
        for (int j = 0; j < 4; ++j) {
            const int m = m0 + mi * 16 + lh * 4 + j;
            float v = fast_tanh(acc[mi][j] + bb);
            if (last) outf[(size_t)m * 512 + n] = v;
            else      outb[(size_t)m * 512 + n] = f2bf(v);
        }
    }
}

extern "C" void kernel_launch(void* const* d_in, const int* in_sizes, int n_in,
                              void* d_out, int out_size, void* d_ws, size_t ws_size,
                              hipStream_t stream) {
    const int*   ids  = (const int*)d_in[0];
    const float* emb  = (const float*)d_in[1];
    const float* W    = (const float*)d_in[2];
    const float* bias = (const float*)d_in[3];
    float* out = (float*)d_out;

    // ws (ushorts): Wb 524288 | embT 16384000 | PQ 32768000 | hB 33554432 | hA 16777216
    unsigned short* Wb   = (unsigned short*)d_ws;
    unsigned short* embT = Wb + 524288;
    unsigned short* PQ   = embT + 16384000;
    unsigned short* hB   = PQ + 32768000;
    unsigned short* hA   = hB + 33554432;

    wconv<<<512, 256, 0, stream>>>((const float4*)W, (ushort4*)Wb);
    tconv<<<16000, 256, 0, stream>>>((const float4*)emb, (ushort4*)embT);

    // P,Q tables: 2 x [32000 x 512], M=32000 = 125 x 256 exact, K=512 (NT=8)
    gemm256<512, 8, 1><<<500, 512, 0, stream>>>(embT, Wb, bias, PQ);
    lvl1_add<<<16384, 256, 0, stream>>>(ids, PQ, bias, hB);   // level 1 -> hB

    // level 2 (M=32768): 256-tile grid 256 = full machine (NT=16)
    gemm256<1024, 16, 0><<<256, 512, 0, stream>>>(hB, Wb, bias, hA);

    // levels 3-4 (M=16384, 8192): 128-tile, 3 blocks/CU occupancy
    level_gemm<<<512, 256, 0, stream>>>(hA, Wb, bias, hB, 16384);   // lev3 -> hB
    level_gemm<<<256, 256, 0, stream>>>(hB, Wb, bias, hA, 8192);    // lev4 -> hA

    // levels 5..11: Mout = 4096..64; grid = (Mout/64)*8; ping-pong from hA
    int M = 4096;
    for (int l = 5; l <= 11; ++l) {
        const unsigned short* in = (l & 1) ? hA : hB;
        unsigned short*       ob = (l & 1) ? hB : hA;
        small_gemm<<<(M / 64) * 8, 256, 0, stream>>>(in, Wb, bias, ob, out,
                                                     l == 11 ? 1 : 0);
        M >>= 1;
    }
}